// Round 1
// baseline (161.590 us; speedup 1.0000x reference)
//
#include <hip/hip_runtime.h>

#define D     128
#define DP1   129
#define KN    10
#define MCAND 8
#define GSZ   100000.0f

__device__ __forceinline__ float sigmoidf_(float x) {
    return 1.0f / (1.0f + __expf(-x));
}

// ---------------------------------------------------------------------------
// Kernel 1: per-seed SAGE embedding row, accumulated into ssum[128].
// One block per seed slot; pad index (node == N) contributes zero.
// ---------------------------------------------------------------------------
__global__ __launch_bounds__(128) void seed_kernel(
    const int*   __restrict__ seeds,
    const int*   __restrict__ all_nodes,
    const float* __restrict__ mask,
    const float* __restrict__ features,
    const int*   __restrict__ neigh,
    const float* __restrict__ Wself,
    const float* __restrict__ Wneigh,
    float*       __restrict__ ssum,
    int N)
{
    const int node = seeds[blockIdx.x];
    if (node >= N || node < 0) return;   // pad row -> zero contribution
    const int t = threadIdx.x;

    __shared__ float xs[D], nb[D];
    xs[t] = features[(size_t)all_nodes[node] * D + t];
    float a = 0.f;
    #pragma unroll
    for (int k = 0; k < KN; ++k)
        a += features[(size_t)neigh[node * KN + k] * D + t];
    nb[t] = a * (1.0f / KN);
    __syncthreads();

    float h = 0.f;
    #pragma unroll 4
    for (int dp = 0; dp < D; ++dp)
        h = fmaf(xs[dp], Wself[dp * D + t], fmaf(nb[dp], Wneigh[dp * D + t], h));
    h = fmaxf(h, 0.f) * mask[node];
    atomicAdd(&ssum[t], h);
}

// ---------------------------------------------------------------------------
// Kernel 2: seeds_mean = sigmoid((ssum / seeds_idx_num) @ W1)   [129]
// ---------------------------------------------------------------------------
__global__ __launch_bounds__(256) void sm_kernel(
    const float* __restrict__ ssum,
    const float* __restrict__ snum,
    const float* __restrict__ W1,
    float*       __restrict__ sm)
{
    __shared__ float s[D];
    const int t = threadIdx.x;
    const float inv = 1.0f / snum[0];
    if (t < D) s[t] = ssum[t] * inv;
    __syncthreads();
    if (t < DP1) {
        float a = 0.f;
        #pragma unroll 4
        for (int dp = 0; dp < D; ++dp)
            a = fmaf(s[dp], W1[dp * DP1 + t], a);
        sm[t] = sigmoidf_(a);
    }
}

// ---------------------------------------------------------------------------
// Kernel 3: per-candidate embedding + sigmoid(h@W3) . seeds_mean -> Q.
// MCAND candidates per block (amortizes weight streaming 8x).
// Thread t owns output dim t; x/nb/h staged in LDS, float4 broadcasts.
// ---------------------------------------------------------------------------
__global__ __launch_bounds__(128) void cand_kernel(
    const int*   __restrict__ cand,
    const int*   __restrict__ all_nodes,
    const float* __restrict__ mask,
    const float* __restrict__ features,
    const int*   __restrict__ neigh,
    const float* __restrict__ Wself,
    const float* __restrict__ Wneigh,
    const float* __restrict__ W3,
    const float* __restrict__ sm,
    float*       __restrict__ Q,
    int C)
{
    const int c0 = blockIdx.x * MCAND;
    const int t  = threadIdx.x;

    __shared__ float z[2 * MCAND][D];   // rows 0..7: x, rows 8..15: nb_mean
    __shared__ float h[MCAND][D];
    __shared__ float red1[MCAND][D];
    __shared__ float red2[MCAND][D];
    __shared__ float smsh[DP1];

    smsh[t] = sm[t];
    if (t == 0) smsh[D] = sm[D];

    float msk[MCAND];
    #pragma unroll
    for (int m = 0; m < MCAND; ++m) {
        const int c    = c0 + m;
        const int node = (c < C) ? cand[c] : cand[0];
        msk[m] = mask[node];
        z[m][t] = features[(size_t)all_nodes[node] * D + t];
        float a = 0.f;
        #pragma unroll
        for (int k = 0; k < KN; ++k)
            a += features[(size_t)neigh[node * KN + k] * D + t];
        z[MCAND + m][t] = a * (1.0f / KN);
    }
    __syncthreads();

    // h[m][t] = relu( sum_dp x[m][dp]*Wself[dp][t] + nb[m][dp]*Wneigh[dp][t] )
    float acc[MCAND];
    #pragma unroll
    for (int m = 0; m < MCAND; ++m) acc[m] = 0.f;

    for (int dp = 0; dp < D; dp += 4) {
        const float ws0 = Wself[(dp + 0) * D + t];
        const float ws1 = Wself[(dp + 1) * D + t];
        const float ws2 = Wself[(dp + 2) * D + t];
        const float ws3 = Wself[(dp + 3) * D + t];
        const float wn0 = Wneigh[(dp + 0) * D + t];
        const float wn1 = Wneigh[(dp + 1) * D + t];
        const float wn2 = Wneigh[(dp + 2) * D + t];
        const float wn3 = Wneigh[(dp + 3) * D + t];
        #pragma unroll
        for (int m = 0; m < MCAND; ++m) {
            const float4 xv = *(const float4*)&z[m][dp];
            const float4 nv = *(const float4*)&z[MCAND + m][dp];
            float a = acc[m];
            a = fmaf(xv.x, ws0, a); a = fmaf(xv.y, ws1, a);
            a = fmaf(xv.z, ws2, a); a = fmaf(xv.w, ws3, a);
            a = fmaf(nv.x, wn0, a); a = fmaf(nv.y, wn1, a);
            a = fmaf(nv.z, wn2, a); a = fmaf(nv.w, wn3, a);
            acc[m] = a;
        }
    }
    #pragma unroll
    for (int m = 0; m < MCAND; ++m)
        h[m][t] = fmaxf(acc[m], 0.f) * msk[m];
    __syncthreads();

    // a_j[m] for column j = t of W3 (columns 0..127)
    #pragma unroll
    for (int m = 0; m < MCAND; ++m) acc[m] = 0.f;
    for (int dp = 0; dp < D; dp += 4) {
        const float w0 = W3[(dp + 0) * DP1 + t];
        const float w1 = W3[(dp + 1) * DP1 + t];
        const float w2 = W3[(dp + 2) * DP1 + t];
        const float w3 = W3[(dp + 3) * DP1 + t];
        #pragma unroll
        for (int m = 0; m < MCAND; ++m) {
            const float4 hv = *(const float4*)&h[m][dp];
            float a = acc[m];
            a = fmaf(hv.x, w0, a); a = fmaf(hv.y, w1, a);
            a = fmaf(hv.z, w2, a); a = fmaf(hv.w, w3, a);
            acc[m] = a;
        }
    }

    // red1: sum_j sm[j]*sigmoid(a_j[m]) ; red2: raw dot for column 128
    const float w128 = W3[t * DP1 + D];
    const float smt  = smsh[t];
    #pragma unroll
    for (int m = 0; m < MCAND; ++m) {
        red1[m][t] = smt * sigmoidf_(acc[m]);
        red2[m][t] = h[m][t] * w128;
    }
    __syncthreads();

    for (int off = 64; off > 0; off >>= 1) {
        if (t < off) {
            #pragma unroll
            for (int m = 0; m < MCAND; ++m) {
                red1[m][t] += red1[m][t + off];
                red2[m][t] += red2[m][t + off];
            }
        }
        __syncthreads();
    }

    if (t < MCAND && (c0 + t) < C) {
        const float dot = red1[t][0] + smsh[D] * sigmoidf_(red2[t][0]);
        Q[c0 + t] = (1.0f - dot) * GSZ;
    }
}

// ---------------------------------------------------------------------------
extern "C" void kernel_launch(void* const* d_in, const int* in_sizes, int n_in,
                              void* d_out, int out_size, void* d_ws, size_t ws_size,
                              hipStream_t stream)
{
    const int*   seeds    = (const int*)  d_in[0];   // (1,S) int32, pad = N
    const float* snum     = (const float*)d_in[1];   // (1,1) = 50.0
    const int*   cand     = (const int*)  d_in[2];   // (C,)
    const int*   allnodes = (const int*)  d_in[3];   // (N,)
    const float* mask     = (const float*)d_in[4];   // (N,1)
    const float* features = (const float*)d_in[5];   // (N,D)
    const int*   neigh    = (const int*)  d_in[6];   // (N,K)
    const float* Wself    = (const float*)d_in[7];   // (D,D)
    const float* Wneigh   = (const float*)d_in[8];   // (D,D)
    const float* W1       = (const float*)d_in[9];   // (D,D+1)
    // d_in[10] = W2 : computed-but-unused in the reference
    const float* W3       = (const float*)d_in[11];  // (D,D+1)

    float* Q    = (float*)d_out;
    float* ssum = (float*)d_ws;          // 128 floats (+pad)
    float* sm   = ssum + 256;            // 129 floats

    const int S = in_sizes[0];
    const int C = in_sizes[2];
    const int N = in_sizes[3];

    hipMemsetAsync(ssum, 0, DP1 * sizeof(float), stream);
    seed_kernel<<<S, 128, 0, stream>>>(seeds, allnodes, mask, features, neigh,
                                       Wself, Wneigh, ssum, N);
    sm_kernel<<<1, 256, 0, stream>>>(ssum, snum, W1, sm);

    const int nblk = (C + MCAND - 1) / MCAND;
    cand_kernel<<<nblk, 128, 0, stream>>>(cand, allnodes, mask, features, neigh,
                                          Wself, Wneigh, W3, sm, Q, C);
}

// Round 2
// 122.633 us; speedup vs baseline: 1.3177x; 1.3177x over previous
//
#include <hip/hip_runtime.h>

#define D     128
#define DP1   129
#define KN    10
#define GSZ   100000.0f

typedef __attribute__((ext_vector_type(8))) short bf16x8;
typedef __attribute__((ext_vector_type(4))) float f32x4;

#define MFMA16(a, b, c) __builtin_amdgcn_mfma_f32_16x16x32_bf16((a), (b), (c), 0, 0, 0)

__device__ __forceinline__ float sigmoidf_(float x) {
    return 1.0f / (1.0f + __expf(-x));
}
__device__ __forceinline__ unsigned short f2bf(float f) {
    unsigned u = __float_as_uint(f);
    u += 0x7FFFu + ((u >> 16) & 1u);          // RNE
    return (unsigned short)(u >> 16);
}
__device__ __forceinline__ float bf2f(short s) {
    return __uint_as_float(((unsigned)(unsigned short)s) << 16);
}

// ---------------------------------------------------------------------------
// Prep A: features fp32 -> bf16 (one bf16x8 per thread)
// ---------------------------------------------------------------------------
__global__ __launch_bounds__(256) void feat2bf_kernel(
    const float* __restrict__ f, unsigned short* __restrict__ o, int n8)
{
    int i = blockIdx.x * 256 + threadIdx.x;
    if (i >= n8) return;
    const float4 a = *(const float4*)(f + (size_t)i * 8);
    const float4 b = *(const float4*)(f + (size_t)i * 8 + 4);
    bf16x8 v;
    v[0] = (short)f2bf(a.x); v[1] = (short)f2bf(a.y);
    v[2] = (short)f2bf(a.z); v[3] = (short)f2bf(a.w);
    v[4] = (short)f2bf(b.x); v[5] = (short)f2bf(b.y);
    v[6] = (short)f2bf(b.z); v[7] = (short)f2bf(b.w);
    *(bf16x8*)(o + (size_t)i * 8) = v;
}

// ---------------------------------------------------------------------------
// Prep B: W2T[128][256] = [Wself;Wneigh]^T (bf16), W3T[144][128] = padded W3^T
// ---------------------------------------------------------------------------
__global__ __launch_bounds__(256) void wprep_kernel(
    const float* __restrict__ Wself, const float* __restrict__ Wneigh,
    const float* __restrict__ W3,
    unsigned short* __restrict__ W2T, unsigned short* __restrict__ W3T)
{
    int t = blockIdx.x * 256 + threadIdx.x;
    if (t < 128 * 256) {
        int n = t >> 8, k = t & 255;
        float v = (k < 128) ? Wself[k * 128 + n] : Wneigh[(k - 128) * 128 + n];
        W2T[n * 256 + k] = f2bf(v);
    } else {
        int u = t - 128 * 256;
        if (u < 144 * 128) {
            int j = u >> 7, k = u & 127;
            float v = (j < DP1) ? W3[k * DP1 + j] : 0.0f;
            W3T[j * 128 + k] = f2bf(v);
        }
    }
}

// ---------------------------------------------------------------------------
// Kernel 1: per-seed SAGE embedding row, accumulated into ssum[128].
// ---------------------------------------------------------------------------
__global__ __launch_bounds__(128) void seed_kernel(
    const int*   __restrict__ seeds,
    const int*   __restrict__ all_nodes,
    const float* __restrict__ mask,
    const float* __restrict__ features,
    const int*   __restrict__ neigh,
    const float* __restrict__ Wself,
    const float* __restrict__ Wneigh,
    float*       __restrict__ ssum,
    int N)
{
    const int node = seeds[blockIdx.x];
    if (node >= N || node < 0) return;   // pad row -> zero contribution
    const int t = threadIdx.x;

    __shared__ float xs[D], nb[D];
    xs[t] = features[(size_t)all_nodes[node] * D + t];
    float a = 0.f;
    #pragma unroll
    for (int k = 0; k < KN; ++k)
        a += features[(size_t)neigh[node * KN + k] * D + t];
    nb[t] = a * (1.0f / KN);
    __syncthreads();

    float h = 0.f;
    #pragma unroll 4
    for (int dp = 0; dp < D; ++dp)
        h = fmaf(xs[dp], Wself[dp * D + t], fmaf(nb[dp], Wneigh[dp * D + t], h));
    h = fmaxf(h, 0.f) * mask[node];
    atomicAdd(&ssum[t], h);
}

// ---------------------------------------------------------------------------
// Kernel 2: sm_pad[144]: sigmoid((ssum/num) @ W1) for j<129, 0 for pad.
// ---------------------------------------------------------------------------
__global__ __launch_bounds__(256) void sm_kernel(
    const float* __restrict__ ssum,
    const float* __restrict__ snum,
    const float* __restrict__ W1,
    float*       __restrict__ smp)
{
    __shared__ float s[D];
    const int t = threadIdx.x;
    const float inv = 1.0f / snum[0];
    if (t < D) s[t] = ssum[t] * inv;
    __syncthreads();
    if (t < DP1) {
        float a = 0.f;
        #pragma unroll 4
        for (int dp = 0; dp < D; ++dp)
            a = fmaf(s[dp], W1[dp * DP1 + t], a);
        smp[t] = sigmoidf_(a);
    } else if (t < 144) {
        smp[t] = 0.0f;
    }
}

// ---------------------------------------------------------------------------
// Kernel 3 (fast path): MFMA candidate kernel.
// 512 thr = 8 waves; 16 candidates/wave, 128/block.
// GEMM1: [16 x 256] @ W2T^T -> h[16][128]; GEMM2: h @ W3T^T -> S[16][144];
// epilogue: Q = (1 - sum_j smp[j]*sigmoid(S[.][j])) * GSZ.
// ---------------------------------------------------------------------------
__global__ __launch_bounds__(512) void cand_mfma_kernel(
    const int*            __restrict__ cand,
    const int*            __restrict__ all_nodes,
    const float*          __restrict__ mask,
    const unsigned short* __restrict__ featb,
    const int*            __restrict__ neigh,
    const unsigned short* __restrict__ W2T,
    const unsigned short* __restrict__ W3T,
    const float*          __restrict__ smp,
    float*                __restrict__ Q,
    int C)
{
    const int lane = threadIdx.x & 63;
    const int wv   = threadIdx.x >> 6;
    const int g    = lane >> 4;
    const int n15  = lane & 15;
    const int cbase = blockIdx.x * 128 + wv * 16;

    // ---- gather A fragments (lane owns row = candidate n15 of this tile) ----
    const int cm   = cbase + n15;
    const int node = cand[(cm < C) ? cm : 0];

    bf16x8 ax[4];
    {
        const unsigned short* xr = featb + (size_t)all_nodes[node] * D + g * 8;
        #pragma unroll
        for (int ks = 0; ks < 4; ++ks)
            ax[ks] = *(const bf16x8*)(xr + ks * 32);
    }

    bf16x8 anb[4];
    {
        float sa[4][8];
        #pragma unroll
        for (int ks = 0; ks < 4; ++ks)
            #pragma unroll
            for (int j = 0; j < 8; ++j) sa[ks][j] = 0.f;

        const int* nr = neigh + node * KN;
        #pragma unroll
        for (int k = 0; k < KN; ++k) {
            const unsigned short* rr = featb + (size_t)nr[k] * D + g * 8;
            #pragma unroll
            for (int ks = 0; ks < 4; ++ks) {
                const bf16x8 v = *(const bf16x8*)(rr + ks * 32);
                #pragma unroll
                for (int j = 0; j < 8; ++j) sa[ks][j] += bf2f(v[j]);
            }
        }
        #pragma unroll
        for (int ks = 0; ks < 4; ++ks)
            #pragma unroll
            for (int j = 0; j < 8; ++j)
                anb[ks][j] = (short)f2bf(sa[ks][j] * (1.0f / KN));
    }

    // ---- GEMM1: K=256 (x | nb), N=128 ----
    f32x4 acc1[8];
    #pragma unroll
    for (int nt = 0; nt < 8; ++nt) acc1[nt] = (f32x4){0.f, 0.f, 0.f, 0.f};

    #pragma unroll
    for (int ks = 0; ks < 8; ++ks) {
        const bf16x8 a = (ks < 4) ? ax[ks] : anb[ks - 4];
        const unsigned short* bp = W2T + n15 * 256 + (ks & 7) * 32 + g * 8;
        #pragma unroll
        for (int nt = 0; nt < 8; ++nt) {
            const bf16x8 b = *(const bf16x8*)(bp + nt * 16 * 256);
            acc1[nt] = MFMA16(a, b, acc1[nt]);
        }
    }

    // ---- relu * mask, stash h (fp32) in LDS for layout change ----
    float mrow[4];
    #pragma unroll
    for (int r = 0; r < 4; ++r) {
        const int cr = cbase + g * 4 + r;
        mrow[r] = (cr < C) ? mask[cand[cr]] : 0.f;
    }

    __shared__ float hl[8][16][132];
    #pragma unroll
    for (int nt = 0; nt < 8; ++nt) {
        const f32x4 v = acc1[nt];
        #pragma unroll
        for (int r = 0; r < 4; ++r)
            hl[wv][g * 4 + r][nt * 16 + n15] = fmaxf(v[r], 0.f) * mrow[r];
    }
    __syncthreads();

    // ---- read h back as A-fragments (row = n15, k-slice = g*8) ----
    bf16x8 ah[4];
    #pragma unroll
    for (int ks = 0; ks < 4; ++ks) {
        const float* p = &hl[wv][n15][ks * 32 + g * 8];
        const f32x4 lo = *(const f32x4*)p;
        const f32x4 hi = *(const f32x4*)(p + 4);
        #pragma unroll
        for (int j = 0; j < 4; ++j) {
            ah[ks][j]     = (short)f2bf(lo[j]);
            ah[ks][4 + j] = (short)f2bf(hi[j]);
        }
    }

    // ---- GEMM2: h[16x128] @ W3pad[128x144] ----
    f32x4 acc2[9];
    #pragma unroll
    for (int jt = 0; jt < 9; ++jt) acc2[jt] = (f32x4){0.f, 0.f, 0.f, 0.f};

    #pragma unroll
    for (int ks = 0; ks < 4; ++ks) {
        const bf16x8 a = ah[ks];
        const unsigned short* bp = W3T + n15 * 128 + ks * 32 + g * 8;
        #pragma unroll
        for (int jt = 0; jt < 9; ++jt) {
            const bf16x8 b = *(const bf16x8*)(bp + jt * 16 * 128);
            acc2[jt] = MFMA16(a, b, acc2[jt]);
        }
    }

    // ---- epilogue: q[m] = sum_j smp[j] * sigmoid(S[m][j]) ----
    float qp[4] = {0.f, 0.f, 0.f, 0.f};
    #pragma unroll
    for (int jt = 0; jt < 9; ++jt) {
        const float smj = smp[jt * 16 + n15];
        const f32x4 v = acc2[jt];
        #pragma unroll
        for (int r = 0; r < 4; ++r)
            qp[r] += smj * sigmoidf_(v[r]);
    }
    #pragma unroll
    for (int off = 8; off >= 1; off >>= 1)
        #pragma unroll
        for (int r = 0; r < 4; ++r)
            qp[r] += __shfl_xor(qp[r], off);

    if (n15 == 0) {
        #pragma unroll
        for (int r = 0; r < 4; ++r) {
            const int cr = cbase + g * 4 + r;
            if (cr < C) Q[cr] = (1.0f - qp[r]) * GSZ;
        }
    }
}

// ---------------------------------------------------------------------------
// Fallback fp32 candidate kernel (round-1 path, used if ws too small)
// ---------------------------------------------------------------------------
#define MCAND 8
__global__ __launch_bounds__(128) void cand_kernel(
    const int*   __restrict__ cand,
    const int*   __restrict__ all_nodes,
    const float* __restrict__ mask,
    const float* __restrict__ features,
    const int*   __restrict__ neigh,
    const float* __restrict__ Wself,
    const float* __restrict__ Wneigh,
    const float* __restrict__ W3,
    const float* __restrict__ sm,
    float*       __restrict__ Q,
    int C)
{
    const int c0 = blockIdx.x * MCAND;
    const int t  = threadIdx.x;

    __shared__ float z[2 * MCAND][D];
    __shared__ float h[MCAND][D];
    __shared__ float red1[MCAND][D];
    __shared__ float red2[MCAND][D];
    __shared__ float smsh[DP1];

    smsh[t] = sm[t];
    if (t == 0) smsh[D] = sm[D];

    float msk[MCAND];
    #pragma unroll
    for (int m = 0; m < MCAND; ++m) {
        const int c    = c0 + m;
        const int node = (c < C) ? cand[c] : cand[0];
        msk[m] = mask[node];
        z[m][t] = features[(size_t)all_nodes[node] * D + t];
        float a = 0.f;
        #pragma unroll
        for (int k = 0; k < KN; ++k)
            a += features[(size_t)neigh[node * KN + k] * D + t];
        z[MCAND + m][t] = a * (1.0f / KN);
    }
    __syncthreads();

    float acc[MCAND];
    #pragma unroll
    for (int m = 0; m < MCAND; ++m) acc[m] = 0.f;
    for (int dp = 0; dp < D; dp += 4) {
        const float ws0 = Wself[(dp + 0) * D + t];
        const float ws1 = Wself[(dp + 1) * D + t];
        const float ws2 = Wself[(dp + 2) * D + t];
        const float ws3 = Wself[(dp + 3) * D + t];
        const float wn0 = Wneigh[(dp + 0) * D + t];
        const float wn1 = Wneigh[(dp + 1) * D + t];
        const float wn2 = Wneigh[(dp + 2) * D + t];
        const float wn3 = Wneigh[(dp + 3) * D + t];
        #pragma unroll
        for (int m = 0; m < MCAND; ++m) {
            const float4 xv = *(const float4*)&z[m][dp];
            const float4 nv = *(const float4*)&z[MCAND + m][dp];
            float a = acc[m];
            a = fmaf(xv.x, ws0, a); a = fmaf(xv.y, ws1, a);
            a = fmaf(xv.z, ws2, a); a = fmaf(xv.w, ws3, a);
            a = fmaf(nv.x, wn0, a); a = fmaf(nv.y, wn1, a);
            a = fmaf(nv.z, wn2, a); a = fmaf(nv.w, wn3, a);
            acc[m] = a;
        }
    }
    #pragma unroll
    for (int m = 0; m < MCAND; ++m)
        h[m][t] = fmaxf(acc[m], 0.f) * msk[m];
    __syncthreads();

    #pragma unroll
    for (int m = 0; m < MCAND; ++m) acc[m] = 0.f;
    for (int dp = 0; dp < D; dp += 4) {
        const float w0 = W3[(dp + 0) * DP1 + t];
        const float w1 = W3[(dp + 1) * DP1 + t];
        const float w2 = W3[(dp + 2) * DP1 + t];
        const float w3 = W3[(dp + 3) * DP1 + t];
        #pragma unroll
        for (int m = 0; m < MCAND; ++m) {
            const float4 hv = *(const float4*)&h[m][dp];
            float a = acc[m];
            a = fmaf(hv.x, w0, a); a = fmaf(hv.y, w1, a);
            a = fmaf(hv.z, w2, a); a = fmaf(hv.w, w3, a);
            acc[m] = a;
        }
    }

    const float w128 = W3[t * DP1 + D];
    const float smt  = smsh[t];
    #pragma unroll
    for (int m = 0; m < MCAND; ++m) {
        red1[m][t] = smt * sigmoidf_(acc[m]);
        red2[m][t] = h[m][t] * w128;
    }
    __syncthreads();

    for (int off = 64; off > 0; off >>= 1) {
        if (t < off) {
            #pragma unroll
            for (int m = 0; m < MCAND; ++m) {
                red1[m][t] += red1[m][t + off];
                red2[m][t] += red2[m][t + off];
            }
        }
        __syncthreads();
    }

    if (t < MCAND && (c0 + t) < C) {
        const float dot = red1[t][0] + smsh[D] * sigmoidf_(red2[t][0]);
        Q[c0 + t] = (1.0f - dot) * GSZ;
    }
}

// ---------------------------------------------------------------------------
extern "C" void kernel_launch(void* const* d_in, const int* in_sizes, int n_in,
                              void* d_out, int out_size, void* d_ws, size_t ws_size,
                              hipStream_t stream)
{
    const int*   seeds    = (const int*)  d_in[0];
    const float* snum     = (const float*)d_in[1];
    const int*   cand     = (const int*)  d_in[2];
    const int*   allnodes = (const int*)  d_in[3];
    const float* mask     = (const float*)d_in[4];
    const float* features = (const float*)d_in[5];
    const int*   neigh    = (const int*)  d_in[6];
    const float* Wself    = (const float*)d_in[7];
    const float* Wneigh   = (const float*)d_in[8];
    const float* W1       = (const float*)d_in[9];
    // d_in[10] = W2 : unused in reference
    const float* W3       = (const float*)d_in[11];

    float* Q = (float*)d_out;

    const int S = in_sizes[0];
    const int C = in_sizes[2];
    const int N = in_sizes[3];

    // ws layout (bytes)
    char* ws = (char*)d_ws;
    float* ssum = (float*)ws;                       // 128 f  @ 0
    float* smp  = (float*)(ws + 512);               // 144 f  @ 512
    const size_t featb_off = 4096;
    const size_t featb_bytes = (size_t)N * D * 2;   // 25.6 MB
    unsigned short* featb = (unsigned short*)(ws + featb_off);
    unsigned short* W2T   = (unsigned short*)(ws + featb_off + featb_bytes);
    unsigned short* W3T   = W2T + 128 * 256;
    const size_t need = featb_off + featb_bytes + 128 * 256 * 2 + 144 * 128 * 2;

    hipMemsetAsync(ssum, 0, 128 * sizeof(float), stream);
    seed_kernel<<<S, 128, 0, stream>>>(seeds, allnodes, mask, features, neigh,
                                       Wself, Wneigh, ssum, N);
    sm_kernel<<<1, 256, 0, stream>>>(ssum, snum, W1, smp);

    if (ws_size >= need) {
        const int n8 = N * D / 8;
        feat2bf_kernel<<<(n8 + 255) / 256, 256, 0, stream>>>(features, featb, n8);
        wprep_kernel<<<(128 * 256 + 144 * 128 + 255) / 256, 256, 0, stream>>>(
            Wself, Wneigh, W3, W2T, W3T);
        const int nblk = (C + 127) / 128;
        cand_mfma_kernel<<<nblk, 512, 0, stream>>>(cand, allnodes, mask, featb,
                                                   neigh, W2T, W3T, smp, Q, C);
    } else {
        const int nblk = (C + MCAND - 1) / MCAND;
        cand_kernel<<<nblk, 128, 0, stream>>>(cand, allnodes, mask, features,
                                              neigh, Wself, Wneigh, W3, smp, Q, C);
    }
}